// Round 8
// baseline (237.192 us; speedup 1.0000x reference)
//
#include <hip/hip_runtime.h>
#include <math.h>

// Attention fwd: Q[N,64] K[N,64] V[N,64] fp32 -> O[N,64] fp32
// R6 (resubmit): fixed-max softmax + fused split-combine.
//  - softmax in exp2 domain with CONSTANT max M2=8 (scores ~N(0,1) scaled,
//    log2-max ~5.5 << 8): no max-reduce, no rescale, no m tracking. bf16 P
//    relative error is scale-invariant -> same accuracy as running max.
//  - partials combine LINEARLY: last-arriving block per q-column (atomic
//    counter in ws, zeroed by prepass) sums partials + normalizes in-kernel.
//  - staging: dbuf global_load_lds(16B), counted vmcnt(4), XOR swizzle
//    (row&7)<<4, pre-swizzled source addresses. setprio around MFMA.
//  - 16-way key split; Q cast folded into main prologue.

typedef __bf16 bf16;
typedef __attribute__((ext_vector_type(4)))  __bf16 bf16x4;
typedef __attribute__((ext_vector_type(8)))  __bf16 bf16x8;
typedef __attribute__((ext_vector_type(16))) float  f32x16;

#define DKc 64
#define DVc 64
#define TK  64
#define QW  32
#define NW  4
#define QB  (QW * NW)   // 128 queries per block
#define SCALE_LOG2E 0.1803368801111204f   // 0.125 * log2(e)
#define M2FIX 8.0f      // fixed log2-domain max

__device__ __forceinline__ f32x16 mfma_bf16(bf16x8 a, bf16x8 b, f32x16 c) {
    return __builtin_amdgcn_mfma_f32_32x32x16_bf16(a, b, c, 0, 0, 0);
}
__device__ __forceinline__ int rp4(int r) {   // PV k-slot permute (involution)
    return ((r >> 2) & 1) * 8 + (r & 3) + ((r >> 3) << 2);
}

// ---------------- prepass: Kb = bf16(K); Vt = bf16 V^T; zero counters ------
__global__ __launch_bounds__(256)
void prepass(const float* __restrict__ K, const float* __restrict__ V,
             bf16* __restrict__ Kb, bf16* __restrict__ Vt,
             int* __restrict__ counters, int N) {
    const int b = blockIdx.x, tid = threadIdx.x;
    if (b == 0 && tid < 64) counters[tid] = 0;
    const int nkb = (N * DKc) / (256 * 4);          // float4 blocks for K
    if (b < nkb) {
        int idx = b * 256 + tid;
        float4 v = ((const float4*)K)[idx];
        bf16x4 w;
        w[0] = (bf16)v.x; w[1] = (bf16)v.y; w[2] = (bf16)v.z; w[3] = (bf16)v.w;
        ((bf16x4*)Kb)[idx] = w;
    } else {
        // V transpose tile: 64 keys x 64 dv -> Vt[dv][T*64 + permuted key]
        const int T = b - nkb;
        __shared__ float sT[64][65];
#pragma unroll
        for (int p = 0; p < 4; ++p) {
            int fi = p * 256 + tid;                 // float4 index in tile
            int e0 = fi * 4;
            int key = e0 >> 6, dv = e0 & 63;
            float4 v = ((const float4*)(V + (size_t)T * 64 * DVc))[fi];
            sT[dv + 0][key] = v.x; sT[dv + 1][key] = v.y;
            sT[dv + 2][key] = v.z; sT[dv + 3][key] = v.w;
        }
        __syncthreads();
#pragma unroll
        for (int w = 0; w < 2; ++w) {
            int vidx = w * 256 + tid;
            int dv = vidx >> 3, j0 = (vidx & 7) * 8;
            bf16x8 o;
#pragma unroll
            for (int i = 0; i < 8; ++i) {
                int j = j0 + i;
                int ks = (j & 48) | rp4(j & 15);
                o[i] = (bf16)sT[dv][ks];
            }
            *(bf16x8*)(Vt + (size_t)dv * N + T * 64 + j0) = o;
        }
    }
}

// ---------------- main flash kernel + fused combine ------------------------
__global__ __launch_bounds__(256, 4)
void attn_fwd_mfma(const float* __restrict__ Q, const bf16* __restrict__ Kb,
                   const bf16* __restrict__ Vt,
                   float* __restrict__ Opart, float* __restrict__ Lpart,
                   int* __restrict__ counters, float* __restrict__ Out,
                   int N, int splits, int chunk) {
    __shared__ __align__(16) short sK[2][TK * DKc];
    __shared__ __align__(16) short sV[2][DVc * TK];
    __shared__ int sIsLast;

    const int tid  = threadIdx.x;
    const int wid  = tid >> 6;
    const int lane = tid & 63;
    const int l31  = lane & 31;
    const int h    = lane >> 5;

    const int qbase = blockIdx.x * QB + wid * QW;
    const int q     = qbase + l31;
    const int sp    = blockIdx.y;

    // Q fragments from fp32: qf[f][j] = Q[q][f*16+h*8+j] * SCALE_LOG2E
    bf16x8 qf[4];
#pragma unroll
    for (int f = 0; f < 4; ++f) {
        const float* qp = Q + (size_t)q * DKc + f * 16 + h * 8;
        float4 a = *(const float4*)qp;
        float4 b = *(const float4*)(qp + 4);
        qf[f][0] = (bf16)(a.x * SCALE_LOG2E); qf[f][1] = (bf16)(a.y * SCALE_LOG2E);
        qf[f][2] = (bf16)(a.z * SCALE_LOG2E); qf[f][3] = (bf16)(a.w * SCALE_LOG2E);
        qf[f][4] = (bf16)(b.x * SCALE_LOG2E); qf[f][5] = (bf16)(b.y * SCALE_LOG2E);
        qf[f][6] = (bf16)(b.z * SCALE_LOG2E); qf[f][7] = (bf16)(b.w * SCALE_LOG2E);
    }

    f32x16 O0 = {0}, O1 = {0};
    float lsum = 0.f;

    const int k0 = sp * chunk;
    int k1 = k0 + chunk; if (k1 > N) k1 = N;
    const int ntiles = (k1 - k0) / TK;

    const char* KbB = (const char*)Kb;
    const char* VtB = (const char*)Vt;
    const size_t vrow = (size_t)N * 2;

    auto stage = [&](int buf, int t0) {
        char* sKb = (char*)&sK[buf][0];
        char* sVb = (char*)&sV[buf][0];
#pragma unroll
        for (int p = 0; p < 2; ++p) {
            int o   = p * 4096 + wid * 1024 + lane * 16;
            int key = o >> 7;
            int so  = o ^ ((key & 7) << 4);
            __builtin_amdgcn_global_load_lds(
                (const __attribute__((address_space(1))) void*)(KbB + (size_t)t0 * 128 + so),
                (__attribute__((address_space(3))) void*)(sKb + p * 4096 + wid * 1024),
                16, 0, 0);
        }
#pragma unroll
        for (int p = 0; p < 2; ++p) {
            int o  = p * 4096 + wid * 1024 + lane * 16;
            int dv = o >> 7;
            int kb = o & 127;
            int so = kb ^ ((dv & 7) << 4);
            __builtin_amdgcn_global_load_lds(
                (const __attribute__((address_space(1))) void*)(VtB + (size_t)dv * vrow + (size_t)t0 * 2 + so),
                (__attribute__((address_space(3))) void*)(sVb + p * 4096 + wid * 1024),
                16, 0, 0);
        }
    };

    stage(0, k0);
    int cur = 0;

    for (int it = 0; it < ntiles; ++it) {
        if (it + 1 < ntiles) {
            stage(cur ^ 1, k0 + (it + 1) * TK);
            asm volatile("s_waitcnt vmcnt(4)" ::: "memory");
        } else {
            asm volatile("s_waitcnt vmcnt(0)" ::: "memory");
        }
        __builtin_amdgcn_sched_barrier(0);
        __builtin_amdgcn_s_barrier();

        const char* sKc = (const char*)&sK[cur][0];
        const char* sVc = (const char*)&sV[cur][0];

        // ---- QK^T: D[key, q]
        f32x16 d0 = {0}, d1 = {0};
        __builtin_amdgcn_s_setprio(1);
#pragma unroll
        for (int f = 0; f < 4; ++f) {
            int keyA = l31, keyB = 32 + l31;
            int ba = ((keyA * 128) + f * 32 + h * 16) ^ ((keyA & 7) << 4);
            int bb = ((keyB * 128) + f * 32 + h * 16) ^ ((keyB & 7) << 4);
            bf16x8 kf0 = *(const bf16x8*)(sKc + ba);
            bf16x8 kf1 = *(const bf16x8*)(sKc + bb);
            d0 = mfma_bf16(kf0, qf[f], d0);
            d1 = mfma_bf16(kf1, qf[f], d1);
        }
        __builtin_amdgcn_s_setprio(0);

        // ---- fixed-max softmax: P = exp2(s - 8), no reduce, no rescale
        float psum = 0.f;
#pragma unroll
        for (int r = 0; r < 16; ++r) {
            d0[r] = __builtin_amdgcn_exp2f(d0[r] - M2FIX); psum += d0[r];
            d1[r] = __builtin_amdgcn_exp2f(d1[r] - M2FIX); psum += d1[r];
        }
        psum += __shfl_xor(psum, 32);
        lsum += psum;

        // ---- pack P -> A frags
        bf16x8 pa[4];
#pragma unroll
        for (int j = 0; j < 8; ++j) {
            pa[0][j] = (bf16)d0[j];
            pa[1][j] = (bf16)d0[8 + j];
            pa[2][j] = (bf16)d1[j];
            pa[3][j] = (bf16)d1[8 + j];
        }

        // ---- PV
        __builtin_amdgcn_s_setprio(1);
#pragma unroll
        for (int kb = 0; kb < 4; ++kb) {
            int dvA = l31, dvB = 32 + l31;
            int ba = ((dvA * 128) + kb * 32 + h * 16) ^ ((dvA & 7) << 4);
            int bb = ((dvB * 128) + kb * 32 + h * 16) ^ ((dvB & 7) << 4);
            bf16x8 vf0 = *(const bf16x8*)(sVc + ba);
            bf16x8 vf1 = *(const bf16x8*)(sVc + bb);
            O0 = mfma_bf16(pa[kb], vf0, O0);
            O1 = mfma_bf16(pa[kb], vf1, O1);
        }
        __builtin_amdgcn_s_setprio(0);

        __builtin_amdgcn_s_barrier();
        cur ^= 1;
    }

    if (splits == 1) {
        float inv = 1.f / lsum;
#pragma unroll
        for (int r = 0; r < 16; ++r) {
            int qr = (r & 3) + 8 * (r >> 2) + 4 * h;
            float fr = __shfl(inv, (lane & 32) | qr);
            int qq = qbase + qr;
            Out[(size_t)qq * DVc + l31]      = O0[r] * fr;
            Out[(size_t)qq * DVc + 32 + l31] = O1[r] * fr;
        }
        return;
    }

    // ---- write partials (linear-combinable: fixed M)
#pragma unroll
    for (int r = 0; r < 16; ++r) {
        int qr = (r & 3) + 8 * (r >> 2) + 4 * h;
        int qq = qbase + qr;
        size_t off = ((size_t)sp * N + qq) * DVc;
        Opart[off + l31]      = O0[r];
        Opart[off + 32 + l31] = O1[r];
    }
    if (lane < 32) Lpart[(size_t)sp * N + q] = lsum;

    // ---- last block per q-column combines + normalizes
    __threadfence();
    if (tid == 0) {
        int old = atomicAdd(&counters[blockIdx.x], 1);
        sIsLast = (old == splits - 1) ? 1 : 0;
    }
    __syncthreads();
    if (sIsLast) {
        __threadfence();
        const int qb0 = blockIdx.x * QB;
        for (int i = tid; i < QB * (DVc / 4); i += 256) {   // 2048 float4
            int qq = qb0 + (i >> 4);
            int d4 = i & 15;
            float4 acc = make_float4(0.f, 0.f, 0.f, 0.f);
            float  L   = 0.f;
            for (int s = 0; s < splits; ++s) {
                const float4 ov = *(const float4*)(Opart + ((size_t)s * N + qq) * DVc + d4 * 4);
                acc.x += ov.x; acc.y += ov.y; acc.z += ov.z; acc.w += ov.w;
                L += Lpart[(size_t)s * N + qq];
            }
            float inv = 1.f / L;
            *(float4*)(Out + (size_t)qq * DVc + d4 * 4) =
                make_float4(acc.x * inv, acc.y * inv, acc.z * inv, acc.w * inv);
        }
    }
}

extern "C" void kernel_launch(void* const* d_in, const int* in_sizes, int n_in,
                              void* d_out, int out_size, void* d_ws, size_t ws_size,
                              hipStream_t stream) {
    const float* Q = (const float*)d_in[0];
    const float* K = (const float*)d_in[1];
    const float* V = (const float*)d_in[2];
    float* Out = (float*)d_out;

    const int N = in_sizes[0] / DKc;   // 8192

    // ws: Kb | Vt (bf16, N*64 each) | Opart | Lpart | counters
    const size_t bfbytes = (size_t)N * DKc * sizeof(short);
    bf16* Kb = (bf16*)d_ws;
    bf16* Vt = (bf16*)((char*)d_ws + bfbytes);
    char* rest = (char*)d_ws + 2 * bfbytes;
    size_t rest_sz = (ws_size > 2 * bfbytes) ? ws_size - 2 * bfbytes : 0;

    int splits = 16;
    while (splits > 1 &&
           (size_t)splits * (size_t)N * (DVc + 1) * sizeof(float) + 256 > rest_sz)
        splits >>= 1;
    int chunk = (N + splits - 1) / splits;
    chunk = ((chunk + TK - 1) / TK) * TK;

    float* Opart = (float*)rest;
    float* Lpart = Opart + (size_t)splits * N * DVc;
    int*   counters = (int*)(Lpart + (size_t)splits * N);

    const int nkb = (N * DKc) / (256 * 4);
    prepass<<<nkb + N / TK, 256, 0, stream>>>(K, V, Kb, Vt, counters, N);

    dim3 grid(N / QB, splits);
    attn_fwd_mfma<<<grid, 256, 0, stream>>>(Q, Kb, Vt, Opart, Lpart, counters,
                                            Out, N, splits, chunk);
}

// Round 10
// 107.094 us; speedup vs baseline: 2.2148x; 2.2148x over previous
//
#include <hip/hip_runtime.h>
#include <math.h>

// Attention fwd: Q[N,64] K[N,64] V[N,64] fp32 -> O[N,64] fp32
// R7 (resubmit): LDS-free main loop (K/V are L2-resident; staging was pure
// overhead — R6 profile: every ds_read_b128 4-way bank-conflicted).
//  - prepass builds FRAGMENT-MAJOR Kf/Vf: per 64-key tile, 512 slots
//    (sub,f|kb,lane) of 16B = exactly the per-lane MFMA operand. PV key
//    permute rp4 baked into Vf. Main loop = 16 fully-coalesced 1KB loads
//    per wave-tile from L2 + 16 MFMA. No LDS, no barriers, no conflicts.
//  - fixed-max softmax in exp2 domain (M=8; verified absmax 4.9e-4 in R6).
//  - separate combine kernel (R6's fused combine collapsed tail parallelism:
//    64 blocks read 33.5MB latency-bound ~140us -> reverted).
//  - 16-way key split; Q cast folded into main prologue; setprio on MFMA.

typedef __bf16 bf16;
typedef __attribute__((ext_vector_type(8)))  __bf16 bf16x8;
typedef __attribute__((ext_vector_type(16))) float  f32x16;

#define DKc 64
#define DVc 64
#define TK  64
#define QB  128     // queries per block (4 waves x 32)
#define SCALE_LOG2E 0.1803368801111204f   // 0.125 * log2(e)
#define M2FIX 8.0f                        // fixed log2-domain max

__device__ __forceinline__ f32x16 mfma_bf16(bf16x8 a, bf16x8 b, f32x16 c) {
    return __builtin_amdgcn_mfma_f32_32x32x16_bf16(a, b, c, 0, 0, 0);
}
__device__ __forceinline__ int rp4(int r) {   // PV k-slot permute (involution)
    return ((r >> 2) & 1) * 8 + (r & 3) + ((r >> 3) << 2);
}

// ---- prepass: fragment-major Kf, Vf (4096 bf16 per 64-key tile each) ------
// Kf slot idx = sub*256 + f*64 + l : Kf[...] = K[tile*64+sub*32+(l&31)]
//                                              [f*16+(l>>5)*8 .. +8]
// Vf slot idx = sub*256 + kb*64 + l: Vf[...][j] =
//     V[tile*64 + kb*16 + rp4((l>>5)*8+j)][sub*32+(l&31)]
__global__ __launch_bounds__(256)
void prepass(const float* __restrict__ K, const float* __restrict__ V,
             bf16* __restrict__ Kf, bf16* __restrict__ Vf, int N) {
    const int b = blockIdx.x, tid = threadIdx.x;
    const int ntile = N / TK;
    if (b < ntile) {
        const size_t tbase = (size_t)b * 4096;
#pragma unroll
        for (int w = 0; w < 2; ++w) {
            int idx = w * 256 + tid;
            int sub = idx >> 8, f = (idx >> 6) & 3, l = idx & 63;
            int h = l >> 5, c = l & 31;
            const float* src = K + (size_t)(b * 64 + sub * 32 + c) * DKc + f * 16 + h * 8;
            float4 a  = *(const float4*)src;
            float4 b4 = *(const float4*)(src + 4);
            bf16x8 o;
            o[0]=(bf16)a.x;  o[1]=(bf16)a.y;  o[2]=(bf16)a.z;  o[3]=(bf16)a.w;
            o[4]=(bf16)b4.x; o[5]=(bf16)b4.y; o[6]=(bf16)b4.z; o[7]=(bf16)b4.w;
            *(bf16x8*)(Kf + tbase + (size_t)idx * 8) = o;
        }
    } else {
        const int T = b - ntile;
        __shared__ float sT[64][65];        // V tile transposed: sT[dv][key]
#pragma unroll
        for (int p = 0; p < 4; ++p) {
            int fi = p * 256 + tid;          // 1024 float4 = 64x64 tile
            int e0 = fi * 4;
            int key = e0 >> 6, dv = e0 & 63;
            float4 v = ((const float4*)(V + (size_t)T * 64 * DVc))[fi];
            sT[dv + 0][key] = v.x; sT[dv + 1][key] = v.y;
            sT[dv + 2][key] = v.z; sT[dv + 3][key] = v.w;
        }
        __syncthreads();
        const size_t tbase = (size_t)T * 4096;
#pragma unroll
        for (int w = 0; w < 2; ++w) {
            int idx = w * 256 + tid;
            int sub = idx >> 8, kb = (idx >> 6) & 3, l = idx & 63;
            int h = l >> 5, c = l & 31;
            bf16x8 o;
#pragma unroll
            for (int j = 0; j < 8; ++j)
                o[j] = (bf16)sT[sub * 32 + c][kb * 16 + rp4(h * 8 + j)];
            *(bf16x8*)(Vf + tbase + (size_t)idx * 8) = o;
        }
    }
}

// ---- main flash kernel: no LDS, no barriers -------------------------------
__global__ __launch_bounds__(256)
void attn_fwd_mfma(const float* __restrict__ Q, const bf16* __restrict__ Kf,
                   const bf16* __restrict__ Vf,
                   float* __restrict__ Opart, float* __restrict__ Lpart,
                   float* __restrict__ Out, int N, int splits, int chunk) {
    const int tid  = threadIdx.x;
    const int wid  = tid >> 6;
    const int lane = tid & 63;
    const int l31  = lane & 31;
    const int h    = lane >> 5;

    const int qbase = blockIdx.x * QB + wid * 32;
    const int q     = qbase + l31;
    const int sp    = blockIdx.y;

    // Q fragments: qf[f][j] = Q[q][f*16+h*8+j] * SCALE_LOG2E
    bf16x8 qf[4];
#pragma unroll
    for (int f = 0; f < 4; ++f) {
        const float* qp = Q + (size_t)q * DKc + f * 16 + h * 8;
        float4 a = *(const float4*)qp;
        float4 b = *(const float4*)(qp + 4);
        qf[f][0] = (bf16)(a.x * SCALE_LOG2E); qf[f][1] = (bf16)(a.y * SCALE_LOG2E);
        qf[f][2] = (bf16)(a.z * SCALE_LOG2E); qf[f][3] = (bf16)(a.w * SCALE_LOG2E);
        qf[f][4] = (bf16)(b.x * SCALE_LOG2E); qf[f][5] = (bf16)(b.y * SCALE_LOG2E);
        qf[f][6] = (bf16)(b.z * SCALE_LOG2E); qf[f][7] = (bf16)(b.w * SCALE_LOG2E);
    }

    f32x16 O0 = {0}, O1 = {0};
    float lsum = 0.f;

    const int k0 = sp * chunk;
    int k1 = k0 + chunk; if (k1 > N) k1 = N;

    for (int t0 = k0; t0 < k1; t0 += TK) {
        const bf16* Kt = Kf + (size_t)(t0 >> 6) * 4096;
        const bf16* Vt = Vf + (size_t)(t0 >> 6) * 4096;

        // ---- QK^T: D[key, q] (coalesced 16B/lane loads, L2-resident)
        f32x16 d0 = {0}, d1 = {0};
        __builtin_amdgcn_s_setprio(1);
#pragma unroll
        for (int f = 0; f < 4; ++f) {
            bf16x8 kv0 = *(const bf16x8*)(Kt + (size_t)(f * 64 + lane) * 8);
            bf16x8 kv1 = *(const bf16x8*)(Kt + (size_t)(256 + f * 64 + lane) * 8);
            d0 = mfma_bf16(kv0, qf[f], d0);
            d1 = mfma_bf16(kv1, qf[f], d1);
        }
        __builtin_amdgcn_s_setprio(0);

        // ---- fixed-max softmax: P = exp2(s - 8)
        float psum = 0.f;
#pragma unroll
        for (int r = 0; r < 16; ++r) {
            d0[r] = __builtin_amdgcn_exp2f(d0[r] - M2FIX); psum += d0[r];
            d1[r] = __builtin_amdgcn_exp2f(d1[r] - M2FIX); psum += d1[r];
        }
        psum += __shfl_xor(psum, 32);
        lsum += psum;

        // ---- pack P -> A frags
        bf16x8 pa[4];
#pragma unroll
        for (int j = 0; j < 8; ++j) {
            pa[0][j] = (bf16)d0[j];
            pa[1][j] = (bf16)d0[8 + j];
            pa[2][j] = (bf16)d1[j];
            pa[3][j] = (bf16)d1[8 + j];
        }

        // ---- PV
        __builtin_amdgcn_s_setprio(1);
#pragma unroll
        for (int kb = 0; kb < 4; ++kb) {
            bf16x8 vv0 = *(const bf16x8*)(Vt + (size_t)(kb * 64 + lane) * 8);
            bf16x8 vv1 = *(const bf16x8*)(Vt + (size_t)(256 + kb * 64 + lane) * 8);
            O0 = mfma_bf16(pa[kb], vv0, O0);
            O1 = mfma_bf16(pa[kb], vv1, O1);
        }
        __builtin_amdgcn_s_setprio(0);
    }

    if (splits == 1) {
        float inv = 1.f / lsum;
#pragma unroll
        for (int r = 0; r < 16; ++r) {
            int qr = (r & 3) + 8 * (r >> 2) + 4 * h;
            float fr = __shfl(inv, (lane & 32) | qr);
            int qq = qbase + qr;
            Out[(size_t)qq * DVc + l31]      = O0[r] * fr;
            Out[(size_t)qq * DVc + 32 + l31] = O1[r] * fr;
        }
    } else {
#pragma unroll
        for (int r = 0; r < 16; ++r) {
            int qr = (r & 3) + 8 * (r >> 2) + 4 * h;
            int qq = qbase + qr;
            size_t off = ((size_t)sp * N + qq) * DVc;
            Opart[off + l31]      = O0[r];
            Opart[off + 32 + l31] = O1[r];
        }
        if (lane < 32) Lpart[(size_t)sp * N + q] = lsum;
    }
}

// ---- combine: linear (fixed max), high-parallelism grid -------------------
__global__ __launch_bounds__(256)
void attn_combine(const float* __restrict__ Opart, const float* __restrict__ Lpart,
                  float* __restrict__ Out, int N, int splits) {
    const int t  = blockIdx.x * blockDim.x + threadIdx.x;  // [0, N*16)
    const int q  = t >> 4;
    const int d4 = t & 15;

    float4 acc = make_float4(0.f, 0.f, 0.f, 0.f);
    float  L = 0.f;
    for (int s = 0; s < splits; ++s) {
        L += Lpart[(size_t)s * N + q];
        float4 ov = *(const float4*)(Opart + ((size_t)s * N + q) * DVc + d4 * 4);
        acc.x += ov.x; acc.y += ov.y; acc.z += ov.z; acc.w += ov.w;
    }
    float inv = 1.f / L;
    *(float4*)(Out + (size_t)q * DVc + d4 * 4) =
        make_float4(acc.x * inv, acc.y * inv, acc.z * inv, acc.w * inv);
}

extern "C" void kernel_launch(void* const* d_in, const int* in_sizes, int n_in,
                              void* d_out, int out_size, void* d_ws, size_t ws_size,
                              hipStream_t stream) {
    const float* Q = (const float*)d_in[0];
    const float* K = (const float*)d_in[1];
    const float* V = (const float*)d_in[2];
    float* Out = (float*)d_out;

    const int N = in_sizes[0] / DKc;   // 8192

    // ws: Kf | Vf (bf16, N*64 each, fragment-major) | Opart | Lpart
    const size_t bfbytes = (size_t)N * DKc * sizeof(short);
    bf16* Kf = (bf16*)d_ws;
    bf16* Vf = (bf16*)((char*)d_ws + bfbytes);
    char* rest = (char*)d_ws + 2 * bfbytes;
    size_t rest_sz = (ws_size > 2 * bfbytes) ? ws_size - 2 * bfbytes : 0;

    int splits = 16;
    while (splits > 1 &&
           (size_t)splits * (size_t)N * (DVc + 1) * sizeof(float) > rest_sz)
        splits >>= 1;
    int chunk = (N + splits - 1) / splits;
    chunk = ((chunk + TK - 1) / TK) * TK;

    float* Opart = (float*)rest;
    float* Lpart = Opart + (size_t)splits * N * DVc;

    const int ntile = N / TK;
    prepass<<<2 * ntile, 256, 0, stream>>>(K, V, Kf, Vf, N);

    dim3 grid(N / QB, splits);
    attn_fwd_mfma<<<grid, 256, 0, stream>>>(Q, Kf, Vf, Opart, Lpart, Out,
                                            N, splits, chunk);
    if (splits > 1) {
        int total = N * 16;
        attn_combine<<<total / 256, 256, 0, stream>>>(Opart, Lpart, Out, N, splits);
    }
}

// Round 11
// 93.747 us; speedup vs baseline: 2.5301x; 1.1424x over previous
//
#include <hip/hip_runtime.h>
#include <math.h>

// Attention fwd: Q[N,64] K[N,64] V[N,64] fp32 -> O[N,64] fp32
// R10: R7 (LDS-free, fragment-major Kf/Vf) + T14 register prefetch:
//  - __launch_bounds__(256,2): unlock VGPR (R7's 76-VGPR alloc forced
//    just-in-time loads -> 2 exposed L2 latencies per tile).
//  - K-fragments double-buffered in registers: tile t+1's K loads issue
//    before tile t's compute. V loads issue at top of tile t, consumed
//    ~400cyc later by PV. Steady state: no exposed load latency.
//  - tree psum (chain 32 -> ~10).
//  - fixed-max softmax exp2 M=8 (verified), separate combine, splits=16.

typedef __bf16 bf16;
typedef __attribute__((ext_vector_type(8)))  __bf16 bf16x8;
typedef __attribute__((ext_vector_type(16))) float  f32x16;

#define DKc 64
#define DVc 64
#define TK  64
#define QB  128     // queries per block (4 waves x 32)
#define SCALE_LOG2E 0.1803368801111204f   // 0.125 * log2(e)
#define M2FIX 8.0f                        // fixed log2-domain max

__device__ __forceinline__ f32x16 mfma_bf16(bf16x8 a, bf16x8 b, f32x16 c) {
    return __builtin_amdgcn_mfma_f32_32x32x16_bf16(a, b, c, 0, 0, 0);
}
__device__ __forceinline__ int rp4(int r) {   // PV k-slot permute (involution)
    return ((r >> 2) & 1) * 8 + (r & 3) + ((r >> 3) << 2);
}

// ---- prepass: fragment-major Kf, Vf (4096 bf16 per 64-key tile each) ------
__global__ __launch_bounds__(256)
void prepass(const float* __restrict__ K, const float* __restrict__ V,
             bf16* __restrict__ Kf, bf16* __restrict__ Vf, int N) {
    const int b = blockIdx.x, tid = threadIdx.x;
    const int ntile = N / TK;
    if (b < ntile) {
        const size_t tbase = (size_t)b * 4096;
#pragma unroll
        for (int w = 0; w < 2; ++w) {
            int idx = w * 256 + tid;
            int sub = idx >> 8, f = (idx >> 6) & 3, l = idx & 63;
            int h = l >> 5, c = l & 31;
            const float* src = K + (size_t)(b * 64 + sub * 32 + c) * DKc + f * 16 + h * 8;
            float4 a  = *(const float4*)src;
            float4 b4 = *(const float4*)(src + 4);
            bf16x8 o;
            o[0]=(bf16)a.x;  o[1]=(bf16)a.y;  o[2]=(bf16)a.z;  o[3]=(bf16)a.w;
            o[4]=(bf16)b4.x; o[5]=(bf16)b4.y; o[6]=(bf16)b4.z; o[7]=(bf16)b4.w;
            *(bf16x8*)(Kf + tbase + (size_t)idx * 8) = o;
        }
    } else {
        const int T = b - ntile;
        __shared__ float sT[64][65];        // V tile transposed: sT[dv][key]
#pragma unroll
        for (int p = 0; p < 4; ++p) {
            int fi = p * 256 + tid;          // 1024 float4 = 64x64 tile
            int e0 = fi * 4;
            int key = e0 >> 6, dv = e0 & 63;
            float4 v = ((const float4*)(V + (size_t)T * 64 * DVc))[fi];
            sT[dv + 0][key] = v.x; sT[dv + 1][key] = v.y;
            sT[dv + 2][key] = v.z; sT[dv + 3][key] = v.w;
        }
        __syncthreads();
        const size_t tbase = (size_t)T * 4096;
#pragma unroll
        for (int w = 0; w < 2; ++w) {
            int idx = w * 256 + tid;
            int sub = idx >> 8, kb = (idx >> 6) & 3, l = idx & 63;
            int h = l >> 5, c = l & 31;
            bf16x8 o;
#pragma unroll
            for (int j = 0; j < 8; ++j)
                o[j] = (bf16)sT[sub * 32 + c][kb * 16 + rp4(h * 8 + j)];
            *(bf16x8*)(Vf + tbase + (size_t)idx * 8) = o;
        }
    }
}

// one attention step on a 64-key tile whose K frags are in kf[], V in vf[]
#define STEP(kf)                                                              \
    {                                                                         \
        f32x16 d0 = {0}, d1 = {0};                                            \
        __builtin_amdgcn_s_setprio(1);                                        \
        _Pragma("unroll")                                                     \
        for (int f = 0; f < 4; ++f) {                                         \
            d0 = mfma_bf16(kf[2*f],   qf[f], d0);                             \
            d1 = mfma_bf16(kf[2*f+1], qf[f], d1);                             \
        }                                                                     \
        __builtin_amdgcn_s_setprio(0);                                        \
        float ps0 = 0.f, ps1 = 0.f, ps2 = 0.f, ps3 = 0.f;                     \
        _Pragma("unroll")                                                     \
        for (int r = 0; r < 16; r += 4) {                                     \
            d0[r]   = __builtin_amdgcn_exp2f(d0[r]   - M2FIX); ps0 += d0[r];  \
            d0[r+1] = __builtin_amdgcn_exp2f(d0[r+1] - M2FIX); ps1 += d0[r+1];\
            d0[r+2] = __builtin_amdgcn_exp2f(d0[r+2] - M2FIX); ps2 += d0[r+2];\
            d0[r+3] = __builtin_amdgcn_exp2f(d0[r+3] - M2FIX); ps3 += d0[r+3];\
            d1[r]   = __builtin_amdgcn_exp2f(d1[r]   - M2FIX); ps0 += d1[r];  \
            d1[r+1] = __builtin_amdgcn_exp2f(d1[r+1] - M2FIX); ps1 += d1[r+1];\
            d1[r+2] = __builtin_amdgcn_exp2f(d1[r+2] - M2FIX); ps2 += d1[r+2];\
            d1[r+3] = __builtin_amdgcn_exp2f(d1[r+3] - M2FIX); ps3 += d1[r+3];\
        }                                                                     \
        float psum = (ps0 + ps1) + (ps2 + ps3);                               \
        psum += __shfl_xor(psum, 32);                                         \
        lsum += psum;                                                         \
        bf16x8 pa[4];                                                         \
        _Pragma("unroll")                                                     \
        for (int j = 0; j < 8; ++j) {                                         \
            pa[0][j] = (bf16)d0[j];                                           \
            pa[1][j] = (bf16)d0[8 + j];                                       \
            pa[2][j] = (bf16)d1[j];                                           \
            pa[3][j] = (bf16)d1[8 + j];                                       \
        }                                                                     \
        __builtin_amdgcn_s_setprio(1);                                        \
        _Pragma("unroll")                                                     \
        for (int kb = 0; kb < 4; ++kb) {                                      \
            O0 = mfma_bf16(pa[kb], vf[2*kb],   O0);                           \
            O1 = mfma_bf16(pa[kb], vf[2*kb+1], O1);                           \
        }                                                                     \
        __builtin_amdgcn_s_setprio(0);                                        \
    }

// ---- main flash kernel: no LDS; register-prefetched fragments -------------
__global__ __launch_bounds__(256, 2)
void attn_fwd_mfma(const float* __restrict__ Q, const bf16* __restrict__ Kf,
                   const bf16* __restrict__ Vf,
                   float* __restrict__ Opart, float* __restrict__ Lpart,
                   float* __restrict__ Out, int N, int splits, int chunk) {
    const int tid  = threadIdx.x;
    const int wid  = tid >> 6;
    const int lane = tid & 63;
    const int l31  = lane & 31;
    const int h    = lane >> 5;

    const int qbase = blockIdx.x * QB + wid * 32;
    const int q     = qbase + l31;
    const int sp    = blockIdx.y;

    // Q fragments: qf[f][j] = Q[q][f*16+h*8+j] * SCALE_LOG2E
    bf16x8 qf[4];
#pragma unroll
    for (int f = 0; f < 4; ++f) {
        const float* qp = Q + (size_t)q * DKc + f * 16 + h * 8;
        float4 a = *(const float4*)qp;
        float4 b = *(const float4*)(qp + 4);
        qf[f][0] = (bf16)(a.x * SCALE_LOG2E); qf[f][1] = (bf16)(a.y * SCALE_LOG2E);
        qf[f][2] = (bf16)(a.z * SCALE_LOG2E); qf[f][3] = (bf16)(a.w * SCALE_LOG2E);
        qf[f][4] = (bf16)(b.x * SCALE_LOG2E); qf[f][5] = (bf16)(b.y * SCALE_LOG2E);
        qf[f][6] = (bf16)(b.z * SCALE_LOG2E); qf[f][7] = (bf16)(b.w * SCALE_LOG2E);
    }

    f32x16 O0 = {0}, O1 = {0};
    float lsum = 0.f;

    const int k0 = sp * chunk;
    int k1 = k0 + chunk; if (k1 > N) k1 = N;
    const int tile0  = k0 >> 6;
    const int ntiles = (k1 - k0) >> 6;

    auto loadK = [&](bf16x8* kf, int tile) {
        const bf16* Kt = Kf + (size_t)tile * 4096;
#pragma unroll
        for (int f = 0; f < 4; ++f) {
            kf[2*f]   = *(const bf16x8*)(Kt + (size_t)(f * 64 + lane) * 8);
            kf[2*f+1] = *(const bf16x8*)(Kt + (size_t)(256 + f * 64 + lane) * 8);
        }
    };
    auto loadV = [&](bf16x8* vf, int tile) {
        const bf16* Vt = Vf + (size_t)tile * 4096;
#pragma unroll
        for (int kb = 0; kb < 4; ++kb) {
            vf[2*kb]   = *(const bf16x8*)(Vt + (size_t)(kb * 64 + lane) * 8);
            vf[2*kb+1] = *(const bf16x8*)(Vt + (size_t)(256 + kb * 64 + lane) * 8);
        }
    };

    bf16x8 kA[8], kB[8], vf[8];
    loadK(kA, tile0);

    for (int it = 0; it < ntiles; it += 2) {
        // ---- even tile (kA): issue V(t), K(t+1) first, then compute
        loadV(vf, tile0 + it);
        if (it + 1 < ntiles) loadK(kB, tile0 + it + 1);
        STEP(kA)
        // ---- odd tile (kB)
        if (it + 1 < ntiles) {
            loadV(vf, tile0 + it + 1);
            if (it + 2 < ntiles) loadK(kA, tile0 + it + 2);
            STEP(kB)
        }
    }

    if (splits == 1) {
        float inv = 1.f / lsum;
#pragma unroll
        for (int r = 0; r < 16; ++r) {
            int qr = (r & 3) + 8 * (r >> 2) + 4 * h;
            float fr = __shfl(inv, (lane & 32) | qr);
            int qq = qbase + qr;
            Out[(size_t)qq * DVc + l31]      = O0[r] * fr;
            Out[(size_t)qq * DVc + 32 + l31] = O1[r] * fr;
        }
    } else {
#pragma unroll
        for (int r = 0; r < 16; ++r) {
            int qr = (r & 3) + 8 * (r >> 2) + 4 * h;
            int qq = qbase + qr;
            size_t off = ((size_t)sp * N + qq) * DVc;
            Opart[off + l31]      = O0[r];
            Opart[off + 32 + l31] = O1[r];
        }
        if (lane < 32) Lpart[(size_t)sp * N + q] = lsum;
    }
}

// ---- combine: linear (fixed max), high-parallelism grid -------------------
__global__ __launch_bounds__(256)
void attn_combine(const float* __restrict__ Opart, const float* __restrict__ Lpart,
                  float* __restrict__ Out, int N, int splits) {
    const int t  = blockIdx.x * blockDim.x + threadIdx.x;  // [0, N*16)
    const int q  = t >> 4;
    const int d4 = t & 15;

    float4 acc = make_float4(0.f, 0.f, 0.f, 0.f);
    float  L = 0.f;
    for (int s = 0; s < splits; ++s) {
        L += Lpart[(size_t)s * N + q];
        float4 ov = *(const float4*)(Opart + ((size_t)s * N + q) * DVc + d4 * 4);
        acc.x += ov.x; acc.y += ov.y; acc.z += ov.z; acc.w += ov.w;
    }
    float inv = 1.f / L;
    *(float4*)(Out + (size_t)q * DVc + d4 * 4) =
        make_float4(acc.x * inv, acc.y * inv, acc.z * inv, acc.w * inv);
}

extern "C" void kernel_launch(void* const* d_in, const int* in_sizes, int n_in,
                              void* d_out, int out_size, void* d_ws, size_t ws_size,
                              hipStream_t stream) {
    const float* Q = (const float*)d_in[0];
    const float* K = (const float*)d_in[1];
    const float* V = (const float*)d_in[2];
    float* Out = (float*)d_out;

    const int N = in_sizes[0] / DKc;   // 8192

    // ws: Kf | Vf (bf16, N*64 each, fragment-major) | Opart | Lpart
    const size_t bfbytes = (size_t)N * DKc * sizeof(short);
    bf16* Kf = (bf16*)d_ws;
    bf16* Vf = (bf16*)((char*)d_ws + bfbytes);
    char* rest = (char*)d_ws + 2 * bfbytes;
    size_t rest_sz = (ws_size > 2 * bfbytes) ? ws_size - 2 * bfbytes : 0;

    int splits = 16;
    while (splits > 1 &&
           (size_t)splits * (size_t)N * (DVc + 1) * sizeof(float) > rest_sz)
        splits >>= 1;
    int chunk = (N + splits - 1) / splits;
    chunk = ((chunk + TK - 1) / TK) * TK;

    float* Opart = (float*)rest;
    float* Lpart = Opart + (size_t)splits * N * DVc;

    const int ntile = N / TK;
    prepass<<<2 * ntile, 256, 0, stream>>>(K, V, Kf, Vf, N);

    dim3 grid(N / QB, splits);
    attn_fwd_mfma<<<grid, 256, 0, stream>>>(Q, Kf, Vf, Opart, Lpart, Out,
                                            N, splits, chunk);
    if (splits > 1) {
        int total = N * 16;
        attn_combine<<<total / 256, 256, 0, stream>>>(Opart, Lpart, Out, N, splits);
    }
}

// Round 12
// 89.549 us; speedup vs baseline: 2.6487x; 1.0469x over previous
//
#include <hip/hip_runtime.h>
#include <math.h>

// Attention fwd: Q[N,64] K[N,64] V[N,64] fp32 -> O[N,64] fp32
// R11: R10 + within-tile SM||PV pipeline + deferred psum shuffle + splits=8.
//  - STEP pipelined: QK -> SM(d0) -> PV(kb0,1) -> SM(d1) [overlaps PV MFMAs]
//    -> PV(kb2,3). MFMA and VALU are separate pipes; d1-softmax hides under
//    the first PV half. No extra VGPR.
//  - psum cross-half shfl_xor moved out of the K-loop (once, in epilogue).
//  - splits=8: 512 blocks = 2/CU exactly (single residency pass), 16
//    tiles/wave, combine traffic halved.
//  - Kept from R10: LDS-free fragment-major Kf/Vf, K-dbuf + V-prefetch in
//    registers (T14), fixed-max exp2 softmax M=8, launch_bounds(256,2).

typedef __bf16 bf16;
typedef __attribute__((ext_vector_type(8)))  __bf16 bf16x8;
typedef __attribute__((ext_vector_type(16))) float  f32x16;

#define DKc 64
#define DVc 64
#define TK  64
#define QB  128     // queries per block (4 waves x 32)
#define SCALE_LOG2E 0.1803368801111204f   // 0.125 * log2(e)
#define M2FIX 8.0f                        // fixed log2-domain max

__device__ __forceinline__ f32x16 mfma_bf16(bf16x8 a, bf16x8 b, f32x16 c) {
    return __builtin_amdgcn_mfma_f32_32x32x16_bf16(a, b, c, 0, 0, 0);
}
__device__ __forceinline__ int rp4(int r) {   // PV k-slot permute (involution)
    return ((r >> 2) & 1) * 8 + (r & 3) + ((r >> 3) << 2);
}

// ---- prepass: fragment-major Kf, Vf (4096 bf16 per 64-key tile each) ------
__global__ __launch_bounds__(256)
void prepass(const float* __restrict__ K, const float* __restrict__ V,
             bf16* __restrict__ Kf, bf16* __restrict__ Vf, int N) {
    const int b = blockIdx.x, tid = threadIdx.x;
    const int ntile = N / TK;
    if (b < ntile) {
        const size_t tbase = (size_t)b * 4096;
#pragma unroll
        for (int w = 0; w < 2; ++w) {
            int idx = w * 256 + tid;
            int sub = idx >> 8, f = (idx >> 6) & 3, l = idx & 63;
            int h = l >> 5, c = l & 31;
            const float* src = K + (size_t)(b * 64 + sub * 32 + c) * DKc + f * 16 + h * 8;
            float4 a  = *(const float4*)src;
            float4 b4 = *(const float4*)(src + 4);
            bf16x8 o;
            o[0]=(bf16)a.x;  o[1]=(bf16)a.y;  o[2]=(bf16)a.z;  o[3]=(bf16)a.w;
            o[4]=(bf16)b4.x; o[5]=(bf16)b4.y; o[6]=(bf16)b4.z; o[7]=(bf16)b4.w;
            *(bf16x8*)(Kf + tbase + (size_t)idx * 8) = o;
        }
    } else {
        const int T = b - ntile;
        __shared__ float sT[64][65];        // V tile transposed: sT[dv][key]
#pragma unroll
        for (int p = 0; p < 4; ++p) {
            int fi = p * 256 + tid;          // 1024 float4 = 64x64 tile
            int e0 = fi * 4;
            int key = e0 >> 6, dv = e0 & 63;
            float4 v = ((const float4*)(V + (size_t)T * 64 * DVc))[fi];
            sT[dv + 0][key] = v.x; sT[dv + 1][key] = v.y;
            sT[dv + 2][key] = v.z; sT[dv + 3][key] = v.w;
        }
        __syncthreads();
        const size_t tbase = (size_t)T * 4096;
#pragma unroll
        for (int w = 0; w < 2; ++w) {
            int idx = w * 256 + tid;
            int sub = idx >> 8, kb = (idx >> 6) & 3, l = idx & 63;
            int h = l >> 5, c = l & 31;
            bf16x8 o;
#pragma unroll
            for (int j = 0; j < 8; ++j)
                o[j] = (bf16)sT[sub * 32 + c][kb * 16 + rp4(h * 8 + j)];
            *(bf16x8*)(Vf + tbase + (size_t)idx * 8) = o;
        }
    }
}

// one attention step, within-tile pipelined: SM(d1) overlaps PV(kb=0,1)
#define STEP(kf)                                                              \
    {                                                                         \
        f32x16 d0 = {0}, d1 = {0};                                            \
        __builtin_amdgcn_s_setprio(1);                                        \
        _Pragma("unroll")                                                     \
        for (int f = 0; f < 4; ++f) {                                         \
            d0 = mfma_bf16(kf[2*f],   qf[f], d0);                             \
            d1 = mfma_bf16(kf[2*f+1], qf[f], d1);                             \
        }                                                                     \
        __builtin_amdgcn_s_setprio(0);                                        \
        /* SM first half (d0) */                                              \
        _Pragma("unroll")                                                     \
        for (int r = 0; r < 16; r += 4) {                                     \
            d0[r]   = __builtin_amdgcn_exp2f(d0[r]   - M2FIX); ps0 += d0[r];  \
            d0[r+1] = __builtin_amdgcn_exp2f(d0[r+1] - M2FIX); ps1 += d0[r+1];\
            d0[r+2] = __builtin_amdgcn_exp2f(d0[r+2] - M2FIX); ps2 += d0[r+2];\
            d0[r+3] = __builtin_amdgcn_exp2f(d0[r+3] - M2FIX); ps3 += d0[r+3];\
        }                                                                     \
        bf16x8 pa0, pa1;                                                      \
        _Pragma("unroll")                                                     \
        for (int j = 0; j < 8; ++j) { pa0[j] = (bf16)d0[j];                   \
                                      pa1[j] = (bf16)d0[8 + j]; }             \
        /* PV first half (kb=0,1) — d1 softmax below overlaps these MFMAs */  \
        __builtin_amdgcn_s_setprio(1);                                        \
        O0 = mfma_bf16(pa0, vf[0], O0);                                       \
        O1 = mfma_bf16(pa0, vf[1], O1);                                       \
        O0 = mfma_bf16(pa1, vf[2], O0);                                       \
        O1 = mfma_bf16(pa1, vf[3], O1);                                       \
        __builtin_amdgcn_s_setprio(0);                                        \
        /* SM second half (d1) */                                             \
        _Pragma("unroll")                                                     \
        for (int r = 0; r < 16; r += 4) {                                     \
            d1[r]   = __builtin_amdgcn_exp2f(d1[r]   - M2FIX); ps0 += d1[r];  \
            d1[r+1] = __builtin_amdgcn_exp2f(d1[r+1] - M2FIX); ps1 += d1[r+1];\
            d1[r+2] = __builtin_amdgcn_exp2f(d1[r+2] - M2FIX); ps2 += d1[r+2];\
            d1[r+3] = __builtin_amdgcn_exp2f(d1[r+3] - M2FIX); ps3 += d1[r+3];\
        }                                                                     \
        bf16x8 pa2, pa3;                                                      \
        _Pragma("unroll")                                                     \
        for (int j = 0; j < 8; ++j) { pa2[j] = (bf16)d1[j];                   \
                                      pa3[j] = (bf16)d1[8 + j]; }             \
        /* PV second half (kb=2,3) */                                         \
        __builtin_amdgcn_s_setprio(1);                                        \
        O0 = mfma_bf16(pa2, vf[4], O0);                                       \
        O1 = mfma_bf16(pa2, vf[5], O1);                                       \
        O0 = mfma_bf16(pa3, vf[6], O0);                                       \
        O1 = mfma_bf16(pa3, vf[7], O1);                                       \
        __builtin_amdgcn_s_setprio(0);                                        \
    }

// ---- main flash kernel: no LDS; register-prefetched fragments -------------
__global__ __launch_bounds__(256, 2)
void attn_fwd_mfma(const float* __restrict__ Q, const bf16* __restrict__ Kf,
                   const bf16* __restrict__ Vf,
                   float* __restrict__ Opart, float* __restrict__ Lpart,
                   float* __restrict__ Out, int N, int splits, int chunk) {
    const int tid  = threadIdx.x;
    const int wid  = tid >> 6;
    const int lane = tid & 63;
    const int l31  = lane & 31;
    const int h    = lane >> 5;

    const int qbase = blockIdx.x * QB + wid * 32;
    const int q     = qbase + l31;
    const int sp    = blockIdx.y;

    // Q fragments: qf[f][j] = Q[q][f*16+h*8+j] * SCALE_LOG2E
    bf16x8 qf[4];
#pragma unroll
    for (int f = 0; f < 4; ++f) {
        const float* qp = Q + (size_t)q * DKc + f * 16 + h * 8;
        float4 a = *(const float4*)qp;
        float4 b = *(const float4*)(qp + 4);
        qf[f][0] = (bf16)(a.x * SCALE_LOG2E); qf[f][1] = (bf16)(a.y * SCALE_LOG2E);
        qf[f][2] = (bf16)(a.z * SCALE_LOG2E); qf[f][3] = (bf16)(a.w * SCALE_LOG2E);
        qf[f][4] = (bf16)(b.x * SCALE_LOG2E); qf[f][5] = (bf16)(b.y * SCALE_LOG2E);
        qf[f][6] = (bf16)(b.z * SCALE_LOG2E); qf[f][7] = (bf16)(b.w * SCALE_LOG2E);
    }

    f32x16 O0 = {0}, O1 = {0};
    float ps0 = 0.f, ps1 = 0.f, ps2 = 0.f, ps3 = 0.f;   // per-half partial sums

    const int k0 = sp * chunk;
    int k1 = k0 + chunk; if (k1 > N) k1 = N;
    const int tile0  = k0 >> 6;
    const int ntiles = (k1 - k0) >> 6;

    auto loadK = [&](bf16x8* kf, int tile) {
        const bf16* Kt = Kf + (size_t)tile * 4096;
#pragma unroll
        for (int f = 0; f < 4; ++f) {
            kf[2*f]   = *(const bf16x8*)(Kt + (size_t)(f * 64 + lane) * 8);
            kf[2*f+1] = *(const bf16x8*)(Kt + (size_t)(256 + f * 64 + lane) * 8);
        }
    };
    auto loadV = [&](bf16x8* vf, int tile) {
        const bf16* Vt = Vf + (size_t)tile * 4096;
#pragma unroll
        for (int kb = 0; kb < 4; ++kb) {
            vf[2*kb]   = *(const bf16x8*)(Vt + (size_t)(kb * 64 + lane) * 8);
            vf[2*kb+1] = *(const bf16x8*)(Vt + (size_t)(256 + kb * 64 + lane) * 8);
        }
    };

    bf16x8 kA[8], kB[8], vf[8];
    loadK(kA, tile0);

    for (int it = 0; it < ntiles; it += 2) {
        // ---- even tile (kA): issue V(t), K(t+1) first, then compute
        loadV(vf, tile0 + it);
        if (it + 1 < ntiles) loadK(kB, tile0 + it + 1);
        STEP(kA)
        // ---- odd tile (kB)
        if (it + 1 < ntiles) {
            loadV(vf, tile0 + it + 1);
            if (it + 2 < ntiles) loadK(kA, tile0 + it + 2);
            STEP(kB)
        }
    }

    // cross-half psum reduce, ONCE (was per tile)
    float lsum = (ps0 + ps1) + (ps2 + ps3);
    lsum += __shfl_xor(lsum, 32);

    if (splits == 1) {
        float inv = 1.f / lsum;
#pragma unroll
        for (int r = 0; r < 16; ++r) {
            int qr = (r & 3) + 8 * (r >> 2) + 4 * h;
            float fr = __shfl(inv, (lane & 32) | qr);
            int qq = qbase + qr;
            Out[(size_t)qq * DVc + l31]      = O0[r] * fr;
            Out[(size_t)qq * DVc + 32 + l31] = O1[r] * fr;
        }
    } else {
#pragma unroll
        for (int r = 0; r < 16; ++r) {
            int qr = (r & 3) + 8 * (r >> 2) + 4 * h;
            int qq = qbase + qr;
            size_t off = ((size_t)sp * N + qq) * DVc;
            Opart[off + l31]      = O0[r];
            Opart[off + 32 + l31] = O1[r];
        }
        if (lane < 32) Lpart[(size_t)sp * N + q] = lsum;
    }
}

// ---- combine: linear (fixed max), high-parallelism grid -------------------
__global__ __launch_bounds__(256)
void attn_combine(const float* __restrict__ Opart, const float* __restrict__ Lpart,
                  float* __restrict__ Out, int N, int splits) {
    const int t  = blockIdx.x * blockDim.x + threadIdx.x;  // [0, N*16)
    const int q  = t >> 4;
    const int d4 = t & 15;

    float4 acc = make_float4(0.f, 0.f, 0.f, 0.f);
    float  L = 0.f;
    for (int s = 0; s < splits; ++s) {
        L += Lpart[(size_t)s * N + q];
        float4 ov = *(const float4*)(Opart + ((size_t)s * N + q) * DVc + d4 * 4);
        acc.x += ov.x; acc.y += ov.y; acc.z += ov.z; acc.w += ov.w;
    }
    float inv = 1.f / L;
    *(float4*)(Out + (size_t)q * DVc + d4 * 4) =
        make_float4(acc.x * inv, acc.y * inv, acc.z * inv, acc.w * inv);
}

extern "C" void kernel_launch(void* const* d_in, const int* in_sizes, int n_in,
                              void* d_out, int out_size, void* d_ws, size_t ws_size,
                              hipStream_t stream) {
    const float* Q = (const float*)d_in[0];
    const float* K = (const float*)d_in[1];
    const float* V = (const float*)d_in[2];
    float* Out = (float*)d_out;

    const int N = in_sizes[0] / DKc;   // 8192

    // ws: Kf | Vf (bf16, N*64 each, fragment-major) | Opart | Lpart
    const size_t bfbytes = (size_t)N * DKc * sizeof(short);
    bf16* Kf = (bf16*)d_ws;
    bf16* Vf = (bf16*)((char*)d_ws + bfbytes);
    char* rest = (char*)d_ws + 2 * bfbytes;
    size_t rest_sz = (ws_size > 2 * bfbytes) ? ws_size - 2 * bfbytes : 0;

    int splits = 8;     // 512 blocks = 2 blocks/CU exactly, single pass
    while (splits > 1 &&
           (size_t)splits * (size_t)N * (DVc + 1) * sizeof(float) > rest_sz)
        splits >>= 1;
    int chunk = (N + splits - 1) / splits;
    chunk = ((chunk + TK - 1) / TK) * TK;

    float* Opart = (float*)rest;
    float* Lpart = Opart + (size_t)splits * N * DVc;

    const int ntile = N / TK;
    prepass<<<2 * ntile, 256, 0, stream>>>(K, V, Kf, Vf, N);

    dim3 grid(N / QB, splits);
    attn_fwd_mfma<<<grid, 256, 0, stream>>>(Q, Kf, Vf, Opart, Lpart, Out,
                                            N, splits, chunk);
    if (splits > 1) {
        int total = N * 16;
        attn_combine<<<total / 256, 256, 0, stream>>>(Opart, Lpart, Out, N, splits);
    }
}